// Round 1
// baseline (120.205 us; speedup 1.0000x reference)
//
#include <hip/hip_runtime.h>

#define BB 4
#define SS 256
#define DD 768
#define DEPC 100
#define HH 12
#define DKK 64

// ---------- K1: u[p][h] = sum_d W_e[p][h*64+d] * w_rel[d] ----------
__global__ __launch_bounds__(256) void k_u(const float* __restrict__ W_e,
                                           const float* __restrict__ w_rel,
                                           float* __restrict__ u) {
    int e = blockIdx.x * 256 + threadIdx.x;
    if (e >= DEPC * HH) return;
    int p = e / HH, h = e % HH;
    const float4* we = (const float4*)(W_e + p * DD + h * DKK);
    const float4* wr = (const float4*)w_rel;
    float acc = 0.f;
#pragma unroll
    for (int c = 0; c < DKK / 4; ++c) {
        float4 a = we[c], b = wr[c];
        acc += a.x * b.x + a.y * b.y + a.z * b.z + a.w * b.w;
    }
    u[e] = acc;
}

// ---------- K2: V = token @ W_v  (1024x768 @ 768x768, fp32 tiled) ----------
#define TM 32
#define TN 64
#define TKK 16
__global__ __launch_bounds__(256) void k_v(const float* __restrict__ A,
                                           const float* __restrict__ Bm,
                                           float* __restrict__ C) {
    __shared__ float As[TKK][TM + 4];  // [k][row], padded
    __shared__ float Bs[TKK][TN];      // [k][col]
    int t = threadIdx.x;
    int tx = t & 15, ty = t >> 4;               // tx: col-quad, ty: row pair
    int r0 = blockIdx.x * TM, c0 = blockIdx.y * TN;
    float acc[2][4] = {};
    for (int k0 = 0; k0 < DD; k0 += TKK) {
        // A tile 32x16: thread reads (row=ty, k=tx) and (row=ty+16, k=tx)
        As[tx][ty]      = A[(r0 + ty) * DD + k0 + tx];
        As[tx][ty + 16] = A[(r0 + ty + 16) * DD + k0 + tx];
        // B tile 16x64, coalesced
        int kb = t >> 6, cb = t & 63;
#pragma unroll
        for (int q = 0; q < 4; ++q)
            Bs[kb + 4 * q][cb] = Bm[(k0 + kb + 4 * q) * DD + c0 + cb];
        __syncthreads();
#pragma unroll
        for (int kk = 0; kk < TKK; ++kk) {
            float a0 = As[kk][2 * ty], a1 = As[kk][2 * ty + 1];
            float4 b = *(const float4*)&Bs[kk][4 * tx];
            acc[0][0] += a0 * b.x; acc[0][1] += a0 * b.y;
            acc[0][2] += a0 * b.z; acc[0][3] += a0 * b.w;
            acc[1][0] += a1 * b.x; acc[1][1] += a1 * b.y;
            acc[1][2] += a1 * b.z; acc[1][3] += a1 * b.w;
        }
        __syncthreads();
    }
#pragma unroll
    for (int m = 0; m < 2; ++m) {
        float4 v = make_float4(acc[m][0], acc[m][1], acc[m][2], acc[m][3]);
        *(float4*)&C[(size_t)(r0 + 2 * ty + m) * DD + c0 + 4 * tx] = v;
    }
}

// ---------- K3: scores[b][h][i][j] = mask ? relu(edge_row . u[:,h]) : -1e6 ----------
__global__ __launch_bounds__(256) void k_sc(const float* __restrict__ edge,
                                            const int* __restrict__ mask,
                                            const float* __restrict__ ug,
                                            float* __restrict__ scores) {
    __shared__ float u[DEPC * HH];  // [p][h], 4.8 KB
    int t = threadIdx.x;
    for (int idx = t; idx < DEPC * HH; idx += 256) u[idx] = ug[idx];
    __syncthreads();
    int i = blockIdx.x, b = blockIdx.y, j = t;
    const float4* row = (const float4*)(edge + (size_t)((b * SS + i) * SS + j) * DEPC);
    float e[DEPC];
#pragma unroll
    for (int c = 0; c < DEPC / 4; ++c) ((float4*)e)[c] = row[c];  // 25 b128 burst
    float acc[HH] = {};
#pragma unroll
    for (int p = 0; p < DEPC; ++p) {
        float ev = e[p];
        float4 u0 = *(const float4*)&u[p * HH];
        float4 u1 = *(const float4*)&u[p * HH + 4];
        float4 u2 = *(const float4*)&u[p * HH + 8];
        acc[0] += ev * u0.x; acc[1]  += ev * u0.y; acc[2]  += ev * u0.z; acc[3]  += ev * u0.w;
        acc[4] += ev * u1.x; acc[5]  += ev * u1.y; acc[6]  += ev * u1.z; acc[7]  += ev * u1.w;
        acc[8] += ev * u2.x; acc[9]  += ev * u2.y; acc[10] += ev * u2.z; acc[11] += ev * u2.w;
    }
    int mk = mask[(b * SS + i) * SS + j];
#pragma unroll
    for (int h = 0; h < HH; ++h) {
        float s = fmaxf(acc[h], 0.f);
        if (mk == 0) s = -1e6f;
        scores[(((size_t)b * HH + h) * SS + i) * SS + j] = s;
    }
}

// ---------- K4: softmax over j + ctx = P@V + relu(token+ctx) ----------
#define GG 4
__global__ __launch_bounds__(256) void k_ctx(const float* __restrict__ scores,
                                             const float* __restrict__ V,
                                             const float* __restrict__ token,
                                             float* __restrict__ out) {
    __shared__ float sc[GG][HH][SS];  // 48 KB: scores then probs in place
    int t = threadIdx.x, b = blockIdx.y, i0 = blockIdx.x * GG;
    for (int idx = t; idx < GG * HH * (SS / 4); idx += 256) {
        int jc = idx & 63, r = idx >> 6;
        int g = r / HH, h = r % HH;
        float4 v = *(const float4*)(scores + (((size_t)b * HH + h) * SS + (i0 + g)) * SS + 4 * jc);
        *(float4*)&sc[g][h][4 * jc] = v;
    }
    __syncthreads();
    // wave-parallel softmax: 48 rows, 4 waves, 12 rows each
    int lane = t & 63, w = t >> 6;
    for (int r = w; r < GG * HH; r += 4) {
        int g = r / HH, h = r % HH;
        float x0 = sc[g][h][lane],       x1 = sc[g][h][lane + 64];
        float x2 = sc[g][h][lane + 128], x3 = sc[g][h][lane + 192];
        float m = fmaxf(fmaxf(x0, x1), fmaxf(x2, x3));
#pragma unroll
        for (int o = 32; o > 0; o >>= 1) m = fmaxf(m, __shfl_xor(m, o, 64));
        x0 = __expf(x0 - m); x1 = __expf(x1 - m);
        x2 = __expf(x2 - m); x3 = __expf(x3 - m);
        float s = x0 + x1 + x2 + x3;
#pragma unroll
        for (int o = 32; o > 0; o >>= 1) s += __shfl_xor(s, o, 64);
        float inv = 1.0f / s;
        sc[g][h][lane] = x0 * inv;       sc[g][h][lane + 64] = x1 * inv;
        sc[g][h][lane + 128] = x2 * inv; sc[g][h][lane + 192] = x3 * inv;
    }
    __syncthreads();
    // ctx: thread owns hd = t, t+256, t+512 (h = hd>>6 uniform per 64-lane group)
    float acc[3][GG] = {};
    for (int j0 = 0; j0 < SS; j0 += 4) {
#pragma unroll
        for (int a = 0; a < 3; ++a) {
            int hd = t + 256 * a;
            int h = hd >> 6;
            float v0 = V[(size_t)(b * SS + j0) * DD + hd];
            float v1 = V[(size_t)(b * SS + j0 + 1) * DD + hd];
            float v2 = V[(size_t)(b * SS + j0 + 2) * DD + hd];
            float v3 = V[(size_t)(b * SS + j0 + 3) * DD + hd];
#pragma unroll
            for (int g = 0; g < GG; ++g) {
                float4 p = *(const float4*)&sc[g][h][j0];  // LDS broadcast
                acc[a][g] += p.x * v0 + p.y * v1 + p.z * v2 + p.w * v3;
            }
        }
    }
#pragma unroll
    for (int a = 0; a < 3; ++a) {
        int hd = t + 256 * a;
#pragma unroll
        for (int g = 0; g < GG; ++g) {
            size_t o = (size_t)(b * SS + i0 + g) * DD + hd;
            out[o] = fmaxf(token[o] + acc[a][g], 0.f);
        }
    }
}

extern "C" void kernel_launch(void* const* d_in, const int* in_sizes, int n_in,
                              void* d_out, int out_size, void* d_ws, size_t ws_size,
                              hipStream_t stream) {
    const float* token = (const float*)d_in[0];
    const float* edge  = (const float*)d_in[1];
    const int*   mask  = (const int*)d_in[2];
    const float* W_v   = (const float*)d_in[3];
    const float* W_e   = (const float*)d_in[4];
    const float* w_rel = (const float*)d_in[5];
    float* out = (float*)d_out;

    char* ws = (char*)d_ws;
    float* u      = (float*)(ws);                                   // 4.8 KB
    float* V      = (float*)(ws + 8192);                            // 3.15 MB
    float* scores = (float*)(ws + 8192 + (size_t)BB * SS * DD * 4); // 12.6 MB

    hipLaunchKernelGGL(k_u,   dim3((DEPC * HH + 255) / 256), dim3(256), 0, stream, W_e, w_rel, u);
    hipLaunchKernelGGL(k_v,   dim3((BB * SS) / TM, DD / TN), dim3(256), 0, stream, token, W_v, V);
    hipLaunchKernelGGL(k_sc,  dim3(SS, BB),                  dim3(256), 0, stream, edge, mask, u, scores);
    hipLaunchKernelGGL(k_ctx, dim3(SS / GG, BB),             dim3(256), 0, stream, scores, V, token, out);
}

// Round 2
// 120.149 us; speedup vs baseline: 1.0005x; 1.0005x over previous
//
#include <hip/hip_runtime.h>

#define BB 4
#define SS 256
#define DD 768
#define DEPC 100
#define HH 12
#define DKK 64

// ---------- K1: u[p][h] = sum_d W_e[p][h*64+d] * w_rel[d] ----------
__global__ __launch_bounds__(256) void k_u(const float* __restrict__ W_e,
                                           const float* __restrict__ w_rel,
                                           float* __restrict__ u) {
    int e = blockIdx.x * 256 + threadIdx.x;
    if (e >= DEPC * HH) return;
    int p = e / HH, h = e % HH;
    const float4* we = (const float4*)(W_e + p * DD + h * DKK);
    const float4* wr = (const float4*)w_rel;
    float acc = 0.f;
#pragma unroll
    for (int c = 0; c < DKK / 4; ++c) {
        float4 a = we[c], b = wr[c];
        acc += a.x * b.x + a.y * b.y + a.z * b.z + a.w * b.w;
    }
    u[e] = acc;
}

// ---------- K2: V = token @ W_v  (1024x768 @ 768x768, fp32 tiled) ----------
#define TM 32
#define TN 64
#define TKK 16
__global__ __launch_bounds__(256) void k_v(const float* __restrict__ A,
                                           const float* __restrict__ Bm,
                                           float* __restrict__ C) {
    __shared__ float As[TKK][TM + 4];  // [k][row], padded
    __shared__ float Bs[TKK][TN];      // [k][col]
    int t = threadIdx.x;
    int tx = t & 15, ty = t >> 4;               // tx: col-quad, ty: row pair
    int r0 = blockIdx.x * TM, c0 = blockIdx.y * TN;
    float acc[2][4] = {};
    for (int k0 = 0; k0 < DD; k0 += TKK) {
        As[tx][ty]      = A[(r0 + ty) * DD + k0 + tx];
        As[tx][ty + 16] = A[(r0 + ty + 16) * DD + k0 + tx];
        int kb = t >> 6, cb = t & 63;
#pragma unroll
        for (int q = 0; q < 4; ++q)
            Bs[kb + 4 * q][cb] = Bm[(k0 + kb + 4 * q) * DD + c0 + cb];
        __syncthreads();
#pragma unroll
        for (int kk = 0; kk < TKK; ++kk) {
            float a0 = As[kk][2 * ty], a1 = As[kk][2 * ty + 1];
            float4 b = *(const float4*)&Bs[kk][4 * tx];
            acc[0][0] += a0 * b.x; acc[0][1] += a0 * b.y;
            acc[0][2] += a0 * b.z; acc[0][3] += a0 * b.w;
            acc[1][0] += a1 * b.x; acc[1][1] += a1 * b.y;
            acc[1][2] += a1 * b.z; acc[1][3] += a1 * b.w;
        }
        __syncthreads();
    }
#pragma unroll
    for (int m = 0; m < 2; ++m) {
        float4 v = make_float4(acc[m][0], acc[m][1], acc[m][2], acc[m][3]);
        *(float4*)&C[(size_t)(r0 + 2 * ty + m) * DD + c0 + 4 * tx] = v;
    }
}

// ---------- K3: scores = mask ? relu(E . u) : -1e6, LDS-staged coalesced ----------
#define CH 128  // rows per chunk

template <int N4>
__device__ __forceinline__ void dotblk(const float* __restrict__ e,
                                       const float* __restrict__ uu,
                                       float acc[HH]) {
#pragma unroll
    for (int p4 = 0; p4 < N4; ++p4) {
        float4 ev = *(const float4*)(e + 4 * p4);
        float evs[4] = {ev.x, ev.y, ev.z, ev.w};
#pragma unroll
        for (int q = 0; q < 4; ++q) {
            const float* up = uu + (4 * p4 + q) * HH;  // p*48B -> 16B aligned
            float4 u0 = *(const float4*)up;
            float4 u1 = *(const float4*)(up + 4);
            float4 u2 = *(const float4*)(up + 8);
            float ev_q = evs[q];
            acc[0]  += ev_q * u0.x; acc[1]  += ev_q * u0.y;
            acc[2]  += ev_q * u0.z; acc[3]  += ev_q * u0.w;
            acc[4]  += ev_q * u1.x; acc[5]  += ev_q * u1.y;
            acc[6]  += ev_q * u1.z; acc[7]  += ev_q * u1.w;
            acc[8]  += ev_q * u2.x; acc[9]  += ev_q * u2.y;
            acc[10] += ev_q * u2.z; acc[11] += ev_q * u2.w;
        }
    }
}

__global__ __launch_bounds__(256) void k_sc(const float* __restrict__ edge,
                                            const int* __restrict__ mask,
                                            const float* __restrict__ ug,
                                            float* __restrict__ scores) {
    __shared__ float buf[CH * DEPC];   // 51.2 KB
    __shared__ float part[CH * HH];    // 6 KB
    __shared__ float u[DEPC * HH];     // 4.8 KB  (total 62.1 KB)
    int t = threadIdx.x;
    int i = blockIdx.x, b = blockIdx.y;
    for (int idx = t; idx < DEPC * HH; idx += 256) u[idx] = ug[idx];
    const float* panel = edge + (size_t)(b * SS + i) * SS * DEPC;
    int r = t & (CH - 1), half = t >> 7;  // half is wave-uniform
    // p-split 48/52 keeps both halves' float4 LDS reads 16B-aligned
    int p0 = half * 48;

    for (int c = 0; c < SS / CH; ++c) {
        __syncthreads();  // buf reuse (and u ready on first iter)
        // stage 128 rows x 100 floats = 3200 float4, fully coalesced
        const float4* src = (const float4*)(panel + (size_t)c * CH * DEPC);
        for (int idx = t; idx < CH * DEPC / 4; idx += 256)
            ((float4*)buf)[idx] = src[idx];
        __syncthreads();

        const float* e = buf + r * DEPC + p0;
        const float* uu = u + p0 * HH;
        float acc[HH] = {};
        if (half) dotblk<13>(e, uu, acc);   // p 48..99
        else      dotblk<12>(e, uu, acc);   // p 0..47

        if (half) {
#pragma unroll
            for (int h = 0; h < HH; ++h) part[r * HH + h] = acc[h];
        }
        __syncthreads();
        if (!half) {
            int j = c * CH + r;
            int mk = mask[(b * SS + i) * SS + j];
#pragma unroll
            for (int h = 0; h < HH; ++h) {
                float s = fmaxf(acc[h] + part[r * HH + h], 0.f);
                if (mk == 0) s = -1e6f;
                scores[(((size_t)b * HH + h) * SS + i) * SS + j] = s;
            }
        }
    }
}

// ---------- K4: softmax over j + ctx = P@V + relu(token+ctx) ----------
#define GG 4
__global__ __launch_bounds__(256) void k_ctx(const float* __restrict__ scores,
                                             const float* __restrict__ V,
                                             const float* __restrict__ token,
                                             float* __restrict__ out) {
    __shared__ float sc[GG][HH][SS];  // 48 KB
    int t = threadIdx.x, b = blockIdx.y, i0 = blockIdx.x * GG;
    for (int idx = t; idx < GG * HH * (SS / 4); idx += 256) {
        int jc = idx & 63, rr = idx >> 6;
        int g = rr / HH, h = rr % HH;
        float4 v = *(const float4*)(scores + (((size_t)b * HH + h) * SS + (i0 + g)) * SS + 4 * jc);
        *(float4*)&sc[g][h][4 * jc] = v;
    }
    __syncthreads();
    int lane = t & 63, w = t >> 6;
    for (int rr = w; rr < GG * HH; rr += 4) {
        int g = rr / HH, h = rr % HH;
        float x0 = sc[g][h][lane],       x1 = sc[g][h][lane + 64];
        float x2 = sc[g][h][lane + 128], x3 = sc[g][h][lane + 192];
        float m = fmaxf(fmaxf(x0, x1), fmaxf(x2, x3));
#pragma unroll
        for (int o = 32; o > 0; o >>= 1) m = fmaxf(m, __shfl_xor(m, o, 64));
        x0 = __expf(x0 - m); x1 = __expf(x1 - m);
        x2 = __expf(x2 - m); x3 = __expf(x3 - m);
        float s = x0 + x1 + x2 + x3;
#pragma unroll
        for (int o = 32; o > 0; o >>= 1) s += __shfl_xor(s, o, 64);
        float inv = 1.0f / s;
        sc[g][h][lane] = x0 * inv;       sc[g][h][lane + 64] = x1 * inv;
        sc[g][h][lane + 128] = x2 * inv; sc[g][h][lane + 192] = x3 * inv;
    }
    __syncthreads();
    float acc[3][GG] = {};
    for (int j0 = 0; j0 < SS; j0 += 4) {
#pragma unroll
        for (int a = 0; a < 3; ++a) {
            int hd = t + 256 * a;
            int h = hd >> 6;
            float v0 = V[(size_t)(b * SS + j0) * DD + hd];
            float v1 = V[(size_t)(b * SS + j0 + 1) * DD + hd];
            float v2 = V[(size_t)(b * SS + j0 + 2) * DD + hd];
            float v3 = V[(size_t)(b * SS + j0 + 3) * DD + hd];
#pragma unroll
            for (int g = 0; g < GG; ++g) {
                float4 p = *(const float4*)&sc[g][h][j0];
                acc[a][g] += p.x * v0 + p.y * v1 + p.z * v2 + p.w * v3;
            }
        }
    }
#pragma unroll
    for (int a = 0; a < 3; ++a) {
        int hd = t + 256 * a;
#pragma unroll
        for (int g = 0; g < GG; ++g) {
            size_t o = (size_t)(b * SS + i0 + g) * DD + hd;
            out[o] = fmaxf(token[o] + acc[a][g], 0.f);
        }
    }
}

extern "C" void kernel_launch(void* const* d_in, const int* in_sizes, int n_in,
                              void* d_out, int out_size, void* d_ws, size_t ws_size,
                              hipStream_t stream) {
    const float* token = (const float*)d_in[0];
    const float* edge  = (const float*)d_in[1];
    const int*   mask  = (const int*)d_in[2];
    const float* W_v   = (const float*)d_in[3];
    const float* W_e   = (const float*)d_in[4];
    const float* w_rel = (const float*)d_in[5];
    float* out = (float*)d_out;

    char* ws = (char*)d_ws;
    float* u      = (float*)(ws);                                   // 4.8 KB
    float* V      = (float*)(ws + 8192);                            // 3.15 MB
    float* scores = (float*)(ws + 8192 + (size_t)BB * SS * DD * 4); // 12.6 MB

    hipLaunchKernelGGL(k_u,   dim3((DEPC * HH + 255) / 256), dim3(256), 0, stream, W_e, w_rel, u);
    hipLaunchKernelGGL(k_v,   dim3((BB * SS) / TM, DD / TN), dim3(256), 0, stream, token, W_v, V);
    hipLaunchKernelGGL(k_sc,  dim3(SS, BB),                  dim3(256), 0, stream, edge, mask, u, scores);
    hipLaunchKernelGGL(k_ctx, dim3(SS / GG, BB),             dim3(256), 0, stream, scores, V, token, out);
}